// Round 6
// baseline (123.291 us; speedup 1.0000x reference)
//
#include <hip/hip_runtime.h>
#include <hip/hip_cooperative_groups.h>
#include <cstdint>

namespace cg = cooperative_groups;

// Problem constants (from reference)
#define B 64
#define P 5000
#define G 300
#define C 20
#define SCALE_F 512.0f
#define IOU_TH 0.5f
#define NSPLIT 8                              // pred chunks per image (measured-best geometry)
#define PCHUNK ((P + NSPLIT - 1) / NSPLIT)    // 625
#define NTA 512
#define SPT ((PCHUNK + NTA - 1) / NTA)        // 2 slots per thread
#define NCHUNK ((G + 63) / 64)                // 5 target wave-chunks
#define SENT 0x7FFFFFFF

// Match numpy float32 semantics exactly: no FMA contraction (hipcc defaults
// to contract=fast). Division stays IEEE (no fast-math).
#pragma clang fp contract(off)

// ---------------------------------------------------------------------------
// Round-6: cooperative fusion of the measured-best round-3 kernel (70.3us).
// Geometry bracketed from both sides: more blocks duplicates staging (R2,
// +9us), fewer blocks starves the chip (R5, +11us) -> NSPLIT=8 x 512thr
// stays. Body is round-3 verbatim (atomic hists, ballot-ranked stable target
// scatter, atomic-cursor pred scatter, scattered global pred reads in the
// match loop — every variant tried against these regressed). Single change:
// the resolve dispatch is fused in via hipLaunchCooperativeKernel +
// grid.sync(), removing one kernel launch + its gap.
// Post-sync, each block resolves ITS OWN chunk's winners (m in [pbase,pend)),
// so the corr=0 store (P1) and the 1.0 flip come from the same block -> same
// L2, no cross-XCD write-write ordering hazard; grid.sync only has to make
// blockfp visible for READING (standard cooperative producer/consumer).
// 512 blocks x 512 thr @ __launch_bounds__(512,4) = exactly 2 blocks/CU
// co-resident (LDS 9.7KB, VGPR<=128) as cooperative launch requires.
// Invariants: stable target order within class (chunk-major + lane order ==
// original index order -> jnp.argmax first-occurrence tie-break preserved);
// bucket-restricted strict-> argmax == reference argmax; "first eligible
// claimant (lowest p) per target wins" == the reference scan; IoU arithmetic
// op-for-op identical (contract off, IEEE div).
// ---------------------------------------------------------------------------
__global__ __launch_bounds__(NTA, 4) void fused_kernel(
    const float* __restrict__ preds,      // [B,P,6]
    const float* __restrict__ labels,     // [B,G,5]
    int* __restrict__ blockfp,            // [B,NSPLIT,G]
    float* __restrict__ out_stats,        // [B,P,3]
    float* __restrict__ out_tcls)         // [B,G]
{
    const int s = blockIdx.x;
    const int b = blockIdx.y;
    const int tid = threadIdx.x;
    const int lane = tid & 63;
    const int w = tid >> 6;

    __shared__ float4 sb[G];              // class-sorted scaled target boxes
    __shared__ float  sa[G];              // areas
    __shared__ short  ssi[G];             // sorted pos -> original target idx
    __shared__ short  cls_s[G];           // target class (original order)
    __shared__ int    chist[NCHUNK][C];   // per-chunk class counts -> excl offsets
    __shared__ int    cnt[C];             // per-class totals
    __shared__ int    so[C + 1];          // target bucket offsets
    __shared__ int    pcnt[C];            // pred histogram -> running offset
    __shared__ int    firstp[G];          // chunk-local lowest claimant
    __shared__ unsigned short psorted[PCHUNK]; // slot -> global pred idx

    const float* lab = labels + (size_t)b * G * 5;
    const float* prd = preds + (size_t)b * P * 6;
    const int pbase = s * PCHUNK;
    const int pend = (pbase + PCHUNK < P) ? pbase + PCHUNK : P;
    const int npred = pend - pbase;

    // ---- phase 1: init + target classes (+ out_tcls from value in hand) ----
    if (tid < NCHUNK * C) ((int*)chist)[tid] = 0;
    if (tid < C) pcnt[tid] = 0;
    if (tid < G) {                        // NTA=512 >= G: single pass, t==tid
        float cf = lab[tid * 5 + 4];
        cls_s[tid] = (short)(int)cf;
        firstp[tid] = SENT;
        if (s == 0) out_tcls[(size_t)b * G + tid] = cf;
    }
    __syncthreads();

    // ---- phase 2: histograms + coalesced dense stats store ----
    if (tid < G) atomicAdd(&chist[tid >> 6][cls_s[tid]], 1);
    int myc[SPT];                          // pred class cached for scatter pass
    #pragma unroll
    for (int k = 0; k < SPT; ++k) {
        myc[k] = -1;
        int p = pbase + k * NTA + tid;
        if (p < pend) {
            // (score, cls) as one 8B load; p-order => coalesced
            float2 sc = *reinterpret_cast<const float2*>(prd + (size_t)p * 6 + 4);
            int c = (int)sc.y;
            myc[k] = c;
            atomicAdd(&pcnt[c], 1);
            size_t ip3 = ((size_t)b * P + p) * 3;
            out_stats[ip3 + 0] = 0.0f;     // winners flipped to 1.0 post-sync
            out_stats[ip3 + 1] = sc.x;
            out_stats[ip3 + 2] = sc.y;
        }
    }
    __syncthreads();

    // ---- phase 3a: per-class chunk scan (20 parallel) + pred scan (1) ----
    if (tid < C) {                         // wave 0: 20 threads, 5 iters each
        int run = 0;
        #pragma unroll
        for (int u = 0; u < NCHUNK; ++u) {
            int v = chist[u][tid]; chist[u][tid] = run; run += v;
        }
        cnt[tid] = run;
    }
    if (tid == 64) {                       // wave 1: pred-class exclusive scan
        int a = 0;
        for (int c = 0; c < C; ++c) { int v = pcnt[c]; pcnt[c] = a; a += v; }
    }
    __syncthreads();

    // ---- phase 3b: class-base scan ----
    if (tid == 0) {
        int a = 0;
        for (int c = 0; c < C; ++c) { so[c] = a; a += cnt[c]; }
        so[C] = a;
    }
    __syncthreads();

    // ---- phase 4: stable target scatter (ballot rank) + pred scatter ----
    if (tid < NCHUNK * 64) {               // waves 0..4 fully active (ballot!)
        int c = (tid < G) ? (int)cls_s[tid] : -1;
        unsigned long long mymask = 0;
        #pragma unroll
        for (int cc = 0; cc < C; ++cc) {
            unsigned long long m = __ballot(c == cc);
            if (c == cc) mymask = m;
        }
        if (tid < G) {
            int rank = chist[tid >> 6][c]
                     + __popcll(mymask & ((1ull << lane) - 1));
            int pos = so[c] + rank;
            float x1 = lab[tid * 5 + 0] * SCALE_F;   // *512 exact (pow2)
            float y1 = lab[tid * 5 + 1] * SCALE_F;
            float x2 = lab[tid * 5 + 2] * SCALE_F;
            float y2 = lab[tid * 5 + 3] * SCALE_F;
            sb[pos] = make_float4(x1, y1, x2, y2);
            sa[pos] = (x2 - x1) * (y2 - y1);
            ssi[pos] = (short)tid;
        }
    }
    #pragma unroll
    for (int k = 0; k < SPT; ++k) {
        int p = pbase + k * NTA + tid;
        if (p < pend) {
            int pos = atomicAdd(&pcnt[myc[k]], 1);   // class from registers
            psorted[pos] = (unsigned short)p;
        }
    }
    __syncthreads();

    // ---- phase 5: match (slot-ordered: lanes mostly same class) ----
    #pragma unroll
    for (int k = 0; k < SPT; ++k) {
        int slot = k * NTA + tid;
        if (slot >= npred) continue;
        int p = psorted[slot];
        const float* pr = prd + (size_t)p * 6;
        float2 q0 = *reinterpret_cast<const float2*>(pr);       // x1,y1
        float2 q1 = *reinterpret_cast<const float2*>(pr + 2);   // x2,y2
        float2 q2 = *reinterpret_cast<const float2*>(pr + 4);   // score,cls
        float px1 = q0.x * SCALE_F;
        float py1 = q0.y * SCALE_F;
        float px2 = q1.x * SCALE_F;
        float py2 = q1.y * SCALE_F;
        float score = q2.x;
        int c = (int)q2.y;
        float parea = (px2 - px1) * (py2 - py1);

        int lo = so[c], hi = so[c + 1];
        float best = -1.0f;
        int bi = -1;
        // bucket preserves original order; strict > keeps FIRST max occurrence
        for (int j = lo; j < hi; ++j) {
            float4 tb = sb[j];                 // few distinct j per wave
            float lx = fmaxf(px1, tb.x);
            float ly = fmaxf(py1, tb.y);
            float rx = fminf(px2, tb.z);
            float ry = fminf(py2, tb.w);
            float wd = fmaxf(rx - lx, 0.0f);
            float ht = fmaxf(ry - ly, 0.0f);
            float inter = wd * ht;
            float uni = (parea + sa[j]) - inter;   // reference assoc order
            float iou = inter / uni;               // IEEE div
            if (iou > best) { best = iou; bi = ssi[j]; }
        }

        bool eligible = (score > 0.0f) && (hi > lo) && (best > IOU_TH);
        if (eligible) atomicMin(&firstp[bi], p);
    }
    __syncthreads();

    // ---- phase 6: dump chunk-local claims (coalesced) ----
    if (tid < G)
        blockfp[((size_t)b * NSPLIT + s) * G + tid] = firstp[tid];

    // ---- grid-wide barrier: all blockfp slices visible for reading ----
    cg::this_grid().sync();

    // ---- phase 7: resolve OWN-chunk winners (same-block 0->1 overwrite) ----
    if (tid < G) {
        const int* fp = blockfp + (size_t)b * NSPLIT * G + tid;
        int m = fp[0];
        #pragma unroll
        for (int u = 1; u < NSPLIT; ++u) m = min(m, fp[u * G]);
        // a pred wins at most one target; only the chunk that owns pred m
        // flips it (same block that stored corr=0 -> same-L2 ordering)
        if (m != SENT && m >= pbase && m < pend)
            out_stats[((size_t)b * P + m) * 3] = 1.0f;
    }
}

extern "C" void kernel_launch(void* const* d_in, const int* in_sizes, int n_in,
                              void* d_out, int out_size, void* d_ws, size_t ws_size,
                              hipStream_t stream) {
    const float* output = (const float*)d_in[0];   // [B,P,6]
    const float* labels = (const float*)d_in[1];   // [B,G,5]

    float* out_stats = (float*)d_out;                       // [B,P,3]
    float* out_tcls  = (float*)d_out + (size_t)B * P * 3;   // [B,G]

    // workspace layout (no init required — each block writes its own slice)
    int* blockfp = (int*)d_ws;                              // B*NSPLIT*G ints

    void* args[] = {(void*)&output, (void*)&labels, (void*)&blockfp,
                    (void*)&out_stats, (void*)&out_tcls};
    hipLaunchCooperativeKernel((const void*)fused_kernel,
                               dim3(NSPLIT, B), dim3(NTA),
                               args, 0, stream);
}

// Round 7
// 70.411 us; speedup vs baseline: 1.7510x; 1.7510x over previous
//
#include <hip/hip_runtime.h>
#include <cstdint>

// Problem constants (from reference)
#define B 64
#define P 5000
#define G 300
#define C 20
#define SCALE_F 512.0f
#define IOU_TH 0.5f
#define NSPLIT 8                              // pred chunks per image (bracketed-best: R2 up, R5 down)
#define PCHUNK ((P + NSPLIT - 1) / NSPLIT)    // 625
#define NTA 512
#define SPT ((PCHUNK + NTA - 1) / NTA)        // 2 pred slots per thread
#define NCHUNK ((G + 63) / 64)                // 5 target wave-chunks
#define SENT 0x7FFFFFFF

// Match numpy float32 semantics exactly: no FMA contraction (hipcc defaults
// to contract=fast). Division stays IEEE (no fast-math).
#pragma clang fp contract(off)

// ---------------------------------------------------------------------------
// Round-7: "no pred sort". R6's coop run gave the first direct counters on
// the R3 body: 11% VALUBusy (~6us of real work) vs ~22us duration -> the
// cost is the 7-phase barrier-drain chain, of which 4 phases exist only to
// class-sort preds. The sort saves ~1.6x on a ~5us inner loop but costs
// ~3 staging phases + scattered psorted-order global re-reads. So:
//  * preds processed in NATURAL order: one coalesced float2x3 load pass,
//    stats stored in the same p-ordered pass, divergent per-lane bucket loop
//    (wave-max ~24 iters vs sorted avg ~15 — acceptable).
//  * targets: proven ballot-rank STABLE class-sort (chunk-major + lane order
//    == original index order -> jnp.argmax first-occurrence tie-break
//    preserved), staged from registers (no label re-loads).
//  * firstp/blockfp indexed in SORTED-target space: the sort is a
//    deterministic function of the image's labels, so all 8 blocks of image
//    b agree; resolve only needs the claimed pred index m, never t. This
//    drops ssi[] from the hot loop (bi = j directly).
//  * 4 barriers total (was 6).
// Two plain dispatches (coop grid.sync measured -53us; R3 shape stays).
// Semantics: bucket-restricted strict-> argmax == reference argmax (others
// masked to -1); "first eligible claimant (lowest p) per target wins" ==
// the reference scan (argmax is detected-independent); IoU arithmetic
// op-for-op identical (contract off, IEEE div).
// ---------------------------------------------------------------------------
__global__ __launch_bounds__(NTA, 4) void match_kernel(
    const float* __restrict__ preds,      // [B,P,6]
    const float* __restrict__ labels,     // [B,G,5]
    int* __restrict__ blockfp,            // [B,NSPLIT,G] (sorted-target space)
    float* __restrict__ out_stats,        // [B,P,3]
    float* __restrict__ out_tcls)         // [B,G]
{
    const int s = blockIdx.x;
    const int b = blockIdx.y;
    const int tid = threadIdx.x;
    const int lane = tid & 63;
    const int w = tid >> 6;

    __shared__ float4 sb[G];              // class-sorted scaled target boxes
    __shared__ float  sa[G];              // areas (sorted order)
    __shared__ int    chist[NCHUNK][C];   // per-wave-chunk target class counts
    __shared__ int    so[C + 1];          // target bucket offsets
    __shared__ int    firstp[G];          // chunk-local lowest claimant (sorted space)

    const float* lab = labels + (size_t)b * G * 5;
    const float* prd = preds + (size_t)b * P * 6;
    const int pbase = s * PCHUNK;
    const int pend = (pbase + PCHUNK < P) ? pbase + PCHUNK : P;

    // ---- P1: target load (registers) + ballot histogram + inits ----
    if (tid < G) firstp[tid] = SENT;

    float tx1 = 0, ty1 = 0, tx2 = 0, ty2 = 0;
    int tc = -1;
    unsigned long long tmask = 0;
    if (tid < NCHUNK * 64) {              // waves 0..4 fully active for ballot
        if (tid < G) {
            tx1 = lab[tid * 5 + 0];
            ty1 = lab[tid * 5 + 1];
            tx2 = lab[tid * 5 + 2];
            ty2 = lab[tid * 5 + 3];
            float cf = lab[tid * 5 + 4];
            tc = (int)cf;
            if (s == 0) out_tcls[(size_t)b * G + tid] = cf;
        }
        #pragma unroll
        for (int cc = 0; cc < C; ++cc) {
            unsigned long long m = __ballot(tc == cc);
            if (tc == cc) tmask = m;                       // keep for scatter
            if (lane == cc) chist[w][cc] = __popcll(m);    // race-free write
        }
    }
    __syncthreads();

    // ---- P2: wave-0 scans: chunk-exclusive per class, then class bases ----
    if (tid < 64) {
        int run = 0;
        if (lane < C) {
            #pragma unroll
            for (int u = 0; u < NCHUNK; ++u) {
                int t = chist[u][lane]; chist[u][lane] = run; run += t;
            }
        }
        int v = (lane < C) ? run : 0;      // inclusive scan over class lanes
        #pragma unroll
        for (int d = 1; d < 32; d <<= 1) {
            int o = __shfl_up(v, d);
            if (lane >= d) v += o;
        }
        if (lane < C) so[lane + 1] = v;
        if (lane == 0) so[0] = 0;
    }
    __syncthreads();

    // ---- P3: stable target scatter from registers (sorted space) ----
    if (tid < G) {
        int rank = chist[w][tc] + __popcll(tmask & ((1ull << lane) - 1));
        int pos = so[tc] + rank;           // stable: chunk-major + lane order
        float x1 = tx1 * SCALE_F;          // *512 exact (pow2)
        float y1 = ty1 * SCALE_F;
        float x2 = tx2 * SCALE_F;
        float y2 = ty2 * SCALE_F;
        sb[pos] = make_float4(x1, y1, x2, y2);
        sa[pos] = (x2 - x1) * (y2 - y1);
    }
    __syncthreads();

    // ---- P4: match, natural pred order (coalesced) + stats store ----
    #pragma unroll
    for (int k = 0; k < SPT; ++k) {
        int p = pbase + k * NTA + tid;
        if (p >= pend) continue;
        const float* pr = prd + (size_t)p * 6;
        float2 q0 = *reinterpret_cast<const float2*>(pr);       // x1,y1
        float2 q1 = *reinterpret_cast<const float2*>(pr + 2);   // x2,y2
        float2 q2 = *reinterpret_cast<const float2*>(pr + 4);   // score,cls
        float px1 = q0.x * SCALE_F;
        float py1 = q0.y * SCALE_F;
        float px2 = q1.x * SCALE_F;
        float py2 = q1.y * SCALE_F;
        float score = q2.x;
        int c = (int)q2.y;
        float parea = (px2 - px1) * (py2 - py1);

        size_t ip3 = ((size_t)b * P + p) * 3;
        out_stats[ip3 + 0] = 0.0f;         // winners flipped to 1.0 by resolve
        out_stats[ip3 + 1] = score;
        out_stats[ip3 + 2] = q2.y;

        int lo = so[c], hi = so[c + 1];    // per-lane bounds (divergent loop)
        float best = -1.0f;
        int bi = -1;
        // sorted order within class == original order; strict > keeps FIRST max
        for (int j = lo; j < hi; ++j) {
            float4 tb = sb[j];
            float lx = fmaxf(px1, tb.x);
            float ly = fmaxf(py1, tb.y);
            float rx = fminf(px2, tb.z);
            float ry = fminf(py2, tb.w);
            float wd = fmaxf(rx - lx, 0.0f);
            float ht = fmaxf(ry - ly, 0.0f);
            float inter = wd * ht;
            float uni = (parea + sa[j]) - inter;   // reference assoc order
            float iou = inter / uni;               // IEEE div
            if (iou > best) { best = iou; bi = j; }
        }

        bool eligible = (score > 0.0f) && (hi > lo) && (best > IOU_TH);
        if (eligible) atomicMin(&firstp[bi], p);   // bi in sorted space
    }
    __syncthreads();

    // ---- P5: dump chunk-local claims (coalesced, sorted space) ----
    if (tid < G)
        blockfp[((size_t)b * NSPLIT + s) * G + tid] = firstp[tid];
}

// ---------------------------------------------------------------------------
// Kernel B: tiny sparse resolve. Thread t min-reduces the NSPLIT chunk-local
// claims for sorted-target t (the sorted space is consistent across chunks:
// deterministic function of the image's labels); if a winner exists, that
// pred gets corr=1.0 (one 4B store; <=300 per image). A pred claims only its
// own argmax target, so lf[t]=p implies p's bi==t and the sparse stores
// never collide. Kernel boundary orders kernel A's stores before these.
// ---------------------------------------------------------------------------
__global__ __launch_bounds__(512) void resolve_kernel(
    const int* __restrict__ blockfp,      // [B,NSPLIT,G]
    float* __restrict__ out_stats)        // [B,P,3]
{
    const int b = blockIdx.x;
    const int t = threadIdx.x;
    if (t >= G) return;

    const int* fp = blockfp + (size_t)b * NSPLIT * G + t;
    int m = fp[0];
    #pragma unroll
    for (int s = 1; s < NSPLIT; ++s) m = min(m, fp[s * G]);

    if (m != SENT)
        out_stats[((size_t)b * P + m) * 3] = 1.0f;
}

extern "C" void kernel_launch(void* const* d_in, const int* in_sizes, int n_in,
                              void* d_out, int out_size, void* d_ws, size_t ws_size,
                              hipStream_t stream) {
    const float* output = (const float*)d_in[0];   // [B,P,6]
    const float* labels = (const float*)d_in[1];   // [B,G,5]

    float* out_stats = (float*)d_out;                       // [B,P,3]
    float* out_tcls  = (float*)d_out + (size_t)B * P * 3;   // [B,G]

    // workspace layout (no init required — each block writes its own slice)
    int* blockfp = (int*)d_ws;                              // B*NSPLIT*G ints

    dim3 grid(NSPLIT, B);
    match_kernel<<<grid, NTA, 0, stream>>>(output, labels, blockfp,
                                           out_stats, out_tcls);
    resolve_kernel<<<dim3(B), 512, 0, stream>>>(blockfp, out_stats);
}